// Round 3
// baseline (739.913 us; speedup 1.0000x reference)
//
#include <hip/hip_runtime.h>
#include <math.h>

// PointPWC multi-scale loss. B=2, scales N={8192,4096,2048,1024}.
// Inputs (B,3,N) fp32 channel-major: pc1_0..3, pc2_0..3, flow_0..3.
// Output: single fp32 scalar.
//
// R3: branchless distance-only top-k (v_med3_f32 chain, 1 instr/slot) +
// lazy index tracking via LDS append buffer (2 ds_write_b32, bank-free) +
// candidate broadcast via v_readlane (no LDS tiles, no tile barriers).
// A+B+D fused into one launch; C (needs cv2/cvw) separate.

#define QPB 64
#define NSLICE 8
#define BLOCK 512
#define NTOT 15360   // 8192+4096+2048+1024
#define CAP 16       // per-thread append-buffer slots
#define SMW 16384    // shared words (64 KB)
#define IOFF 8192    // index-plane offset (words)

typedef unsigned int uint;

struct Params {
  const float* pc1[4];
  const float* pc2[4];
  const float* fl[4];
  float4* cv2;   // [B][NTOT]
  float4* cvw;   // [B][NTOT]
  float* out;
};

__device__ __forceinline__ void map_block(int r, int& s, int& b, int& i0,
                                          int& N, int& off, float& alpha) {
  if (r < 256)      { s = 0; }
  else if (r < 384) { s = 1; r -= 256; }
  else if (r < 448) { s = 2; r -= 384; }
  else              { s = 3; r -= 448; }
  int lg = 7 - s;
  b = r >> lg;
  i0 = (r & ((1 << lg) - 1)) * QPB;
  N = 8192 >> s;
  off = 16384 - (16384 >> s);   // {0, 8192, 12288, 14336}
  alpha = 0.02f * (float)(1 << s);
}

__device__ __forceinline__ float wave_sum(float v) {
  #pragma unroll
  for (int o = 32; o; o >>= 1) v += __shfl_down(v, o, 64);
  return v;
}

__device__ __forceinline__ float rlane(float v, int t) {
  return __int_as_float(__builtin_amdgcn_readlane(__float_as_int(v), t));
}

// Filter this thread's append buffer against threshold thr (keep d <= thr).
// Survivors are exactly the running top-K (plus measure-zero ties).
__device__ __forceinline__ void compact_buf(uint* smem, int tid, uint& cnt,
                                            float thr) {
  int n = (int)cnt, w = 0;
  for (int e = 0; e < n; ++e) {
    uint db = smem[e * BLOCK + tid];
    uint ib = smem[IOFF + e * BLOCK + tid];
    if (__uint_as_float(db) <= thr && w < CAP) {
      smem[w * BLOCK + tid] = db;
      smem[IOFF + w * BLOCK + tid] = ib;
      ++w;
    }
  }
  cnt = (uint)w;
}

// Scan candidate slice [lo,hi) for one query per thread:
// - kd[K]: sorted running top-K distances (branchless med3 chain)
// - LDS append buffer collects (d,idx) candidates (conservative filter)
template <int K>
__device__ void scan_topk(const float* px, const float* py, const float* pz,
                          int lo, int hi, float ax, float ay, float az,
                          float (&kd)[K], uint* smem, int tid, uint& cnt) {
  int lane = tid & 63;
  float cx = px[lo + lane], cy = py[lo + lane], cz = pz[lo + lane];
  for (int c0 = lo; c0 < hi; c0 += 64) {
    float nx = 0.f, ny = 0.f, nz = 0.f;
    if (c0 + 64 < hi) {
      nx = px[c0 + 64 + lane]; ny = py[c0 + 64 + lane];
      nz = pz[c0 + 64 + lane];
    }
    for (int t = 0; t < 64; t += 4) {
      #pragma unroll
      for (int u = 0; u < 4; ++u) {
        float sx = rlane(cx, t + u), sy = rlane(cy, t + u),
              sz = rlane(cz, t + u);
        float dx = ax - sx, dy = ay - sy, dz = az - sz;
        float d = fmaf(dx, dx, fmaf(dy, dy, dz * dz));
        if (d < kd[K - 1]) {   // stale threshold: conservative, never misses
          smem[cnt * BLOCK + tid] = __float_as_uint(d);
          smem[IOFF + cnt * BLOCK + tid] = (uint)(c0 + t + u);
          ++cnt;
        }
        #pragma unroll
        for (int m = K - 1; m >= 1; --m)
          kd[m] = __builtin_amdgcn_fmed3f(d, kd[m - 1], kd[m]);
        kd[0] = fminf(kd[0], d);
      }
      // <=4 appends since last check; headroom: 12+4 <= CAP
      if (__any((int)cnt >= CAP - 4))
        compact_buf(smem, tid, cnt, kd[K - 1]);
    }
    cx = nx; cy = ny; cz = nz;
  }
}

// Final compact + pad buffer slots [cnt,K) with +inf sentinels; barrier so
// wave 0 can read every thread's first K slots as the partial result list.
template <int K>
__device__ void finalize(float (&kd)[K], uint* smem, int tid, uint& cnt) {
  compact_buf(smem, tid, cnt, kd[K - 1]);
  #pragma unroll
  for (int m = 0; m < K; ++m) {
    if (m >= (int)cnt) {
      smem[m * BLOCK + tid] = 0x7F800000u;  // +inf
      smem[IOFF + m * BLOCK + tid] = 0u;
    }
  }
  __syncthreads();
}

// Wave 0: merge the 8 per-slice unsorted lists for query q -> sorted (cd,ci).
template <int K>
__device__ void merge8(float (&cd)[K], uint (&ci)[K], const uint* smem,
                       int q) {
  #pragma unroll
  for (int m = 0; m < K; ++m) { cd[m] = 3.0e38f; ci[m] = 0; }
  for (int w = 0; w < NSLICE; ++w) {
    #pragma unroll
    for (int m = 0; m < K; ++m) {
      int t = w * 64 + q;
      float d = __uint_as_float(smem[m * BLOCK + t]);
      uint idx = smem[IOFF + m * BLOCK + t];
      if (d < cd[K - 1]) {
        #pragma unroll
        for (int mm = K - 1; mm >= 1; --mm) {
          bool up = d < cd[mm - 1];
          bool here = (!up) && (d < cd[mm]);
          float nd = up ? cd[mm - 1] : (here ? d : cd[mm]);
          uint ni = up ? ci[mm - 1] : (here ? idx : ci[mm]);
          cd[mm] = nd; ci[mm] = ni;
        }
        if (d < cd[0]) { ci[0] = idx; cd[0] = d; }
      }
    }
  }
}

__global__ __launch_bounds__(1) void k_zero(float* out) { out[0] = 0.f; }

// pass 0 (A): self-KNN p2 k=10 -> cv2
// pass 1 (B): self-KNN p1 k=10 -> cvw + smoothness
// pass 2 (D): p2 -> warp min (dist2)
__global__ __launch_bounds__(BLOCK) void k_fused(Params P) {
  __shared__ uint smem[SMW];
  int tid = threadIdx.x;
  int q = tid & 63, wv = tid >> 6;
  int pass = blockIdx.x / 480;
  int r = blockIdx.x % 480;
  int s, b, i0, N, off; float alpha;
  map_block(r, s, b, i0, N, off, alpha);
  int sl = N / NSLICE;
  int lo = wv * sl, hi = lo + sl;
  int i = i0 + q;

  if (pass == 0) {
    const float* p2 = P.pc2[s] + b * 3 * N;
    float ax = p2[i], ay = p2[N + i], az = p2[2 * N + i];
    float kd[10];
    #pragma unroll
    for (int m = 0; m < 10; ++m) kd[m] = 3.0e38f;
    uint cnt = 0;
    scan_topk<10>(p2, p2 + N, p2 + 2 * N, lo, hi, ax, ay, az, kd, smem, tid,
                  cnt);
    finalize<10>(kd, smem, tid, cnt);
    if (wv) return;
    float cd[10]; uint ci[10];
    merge8<10>(cd, ci, smem, q);
    float sx = 0.f, sy = 0.f, sz = 0.f;
    #pragma unroll
    for (int m = 0; m < 10; ++m) {
      int j = (int)ci[m];
      sx += p2[j]; sy += p2[N + j]; sz += p2[2 * N + j];
    }
    const float inv9 = 1.f / 9.f;
    P.cv2[b * NTOT + off + i] = make_float4((sx - 10.f * ax) * inv9,
                                            (sy - 10.f * ay) * inv9,
                                            (sz - 10.f * az) * inv9, 0.f);
  } else if (pass == 1) {
    const float* p1 = P.pc1[s] + b * 3 * N;
    const float* fl = P.fl[s] + b * 3 * N;
    float ax = p1[i], ay = p1[N + i], az = p1[2 * N + i];
    float kd[10];
    #pragma unroll
    for (int m = 0; m < 10; ++m) kd[m] = 3.0e38f;
    uint cnt = 0;
    scan_topk<10>(p1, p1 + N, p1 + 2 * N, lo, hi, ax, ay, az, kd, smem, tid,
                  cnt);
    finalize<10>(kd, smem, tid, cnt);
    if (wv) return;
    float cd[10]; uint ci[10];
    merge8<10>(cd, ci, smem, q);
    float fix = fl[i], fiy = fl[N + i], fiz = fl[2 * N + i];
    float wix = ax + fix, wiy = ay + fiy, wiz = az + fiz;
    float sx = 0.f, sy = 0.f, sz = 0.f, smooth = 0.f;
    #pragma unroll
    for (int m = 0; m < 10; ++m) {
      int j = (int)ci[m];
      float flx = fl[j], fly = fl[N + j], flz = fl[2 * N + j];
      sx += p1[j] + flx; sy += p1[N + j] + fly; sz += p1[2 * N + j] + flz;
      if (m < 9) {   // k9 = 9 nearest (sorted list, slots 0..8)
        float gx = flx - fix, gy = fly - fiy, gz = flz - fiz;
        smooth += sqrtf(fmaf(gx, gx, fmaf(gy, gy, gz * gz)));
      }
    }
    const float inv9 = 1.f / 9.f;
    P.cvw[b * NTOT + off + i] = make_float4((sx - 10.f * wix) * inv9,
                                            (sy - 10.f * wiy) * inv9,
                                            (sz - 10.f * wiz) * inv9, 0.f);
    float ssum = wave_sum(smooth * (1.f / 8.f));
    if (q == 0) atomicAdd(P.out, alpha * 0.5f * ssum);
  } else {
    const float* p1 = P.pc1[s] + b * 3 * N;
    const float* fl = P.fl[s] + b * 3 * N;
    const float* p2 = P.pc2[s] + b * 3 * N;
    float ax = p2[i], ay = p2[N + i], az = p2[2 * N + i];
    int lane = q;
    float cx = p1[lo + lane] + fl[lo + lane];
    float cy = p1[N + lo + lane] + fl[N + lo + lane];
    float cz = p1[2 * N + lo + lane] + fl[2 * N + lo + lane];
    float dmin = 3.0e38f;
    for (int c0 = lo; c0 < hi; c0 += 64) {
      float nx = 0.f, ny = 0.f, nz = 0.f;
      if (c0 + 64 < hi) {
        int j = c0 + 64 + lane;
        nx = p1[j] + fl[j];
        ny = p1[N + j] + fl[N + j];
        nz = p1[2 * N + j] + fl[2 * N + j];
      }
      for (int t = 0; t < 64; t += 8) {
        #pragma unroll
        for (int u = 0; u < 8; ++u) {
          float sx = rlane(cx, t + u), sy = rlane(cy, t + u),
                sz = rlane(cz, t + u);
          float dx = ax - sx, dy = ay - sy, dz = az - sz;
          dmin = fminf(dmin, fmaf(dx, dx, fmaf(dy, dy, dz * dz)));
        }
      }
      cx = nx; cy = ny; cz = nz;
    }
    float* sm = (float*)smem;
    sm[tid] = dmin;
    __syncthreads();
    if (wv) return;
    #pragma unroll
    for (int w = 1; w < NSLICE; ++w) dmin = fminf(dmin, sm[w * 64 + q]);
    float msum = wave_sum(dmin);
    if (q == 0) atomicAdd(P.out, alpha * 0.5f * msum);
  }
}

// Pass C: warp -> p2 top-5: dist1 + inverse-distance cv2 interp -> curvature
__global__ __launch_bounds__(BLOCK) void k_cross(Params P) {
  __shared__ uint smem[SMW];
  int tid = threadIdx.x;
  int q = tid & 63, wv = tid >> 6;
  int s, b, i0, N, off; float alpha;
  map_block(blockIdx.x, s, b, i0, N, off, alpha);
  int sl = N / NSLICE;
  int lo = wv * sl, hi = lo + sl;
  int i = i0 + q;
  const float* p1 = P.pc1[s] + b * 3 * N;
  const float* fl = P.fl[s] + b * 3 * N;
  const float* p2 = P.pc2[s] + b * 3 * N;
  float ax = p1[i] + fl[i], ay = p1[N + i] + fl[N + i],
        az = p1[2 * N + i] + fl[2 * N + i];
  float kd[5];
  #pragma unroll
  for (int m = 0; m < 5; ++m) kd[m] = 3.0e38f;
  uint cnt = 0;
  scan_topk<5>(p2, p2 + N, p2 + 2 * N, lo, hi, ax, ay, az, kd, smem, tid,
               cnt);
  finalize<5>(kd, smem, tid, cnt);
  if (wv) return;
  float cd[5]; uint ci[5];
  merge8<5>(cd, ci, smem, q);
  float dist1 = cd[0];
  float wsum = 0.f, ix = 0.f, iy = 0.f, iz = 0.f;
  #pragma unroll
  for (int m = 0; m < 5; ++m) {
    float w = 1.f / (cd[m] + 1e-8f);
    wsum += w;
    float4 cv = P.cv2[b * NTOT + off + (int)ci[m]];
    ix += w * cv.x; iy += w * cv.y; iz += w * cv.z;
  }
  float inv = 1.f / wsum;
  ix *= inv; iy *= inv; iz *= inv;
  float4 cw = P.cvw[b * NTOT + off + i];
  float ex = ix - cw.x, ey = iy - cw.y, ez = iz - cw.z;
  float curv = fmaf(ex, ex, fmaf(ey, ey, ez * ez));
  float csum = wave_sum(dist1 + 0.3f * curv);
  if (q == 0) atomicAdd(P.out, alpha * 0.5f * csum);
}

extern "C" void kernel_launch(void* const* d_in, const int* in_sizes, int n_in,
                              void* d_out, int out_size, void* d_ws,
                              size_t ws_size, hipStream_t stream) {
  Params P;
  for (int s = 0; s < 4; ++s) {
    P.pc1[s] = (const float*)d_in[s];
    P.pc2[s] = (const float*)d_in[4 + s];
    P.fl[s]  = (const float*)d_in[8 + s];
  }
  P.cv2 = (float4*)d_ws;
  P.cvw = (float4*)((char*)d_ws + (size_t)2 * NTOT * sizeof(float4));
  P.out = (float*)d_out;

  k_zero<<<dim3(1), dim3(1), 0, stream>>>(P.out);
  k_fused<<<dim3(1440), dim3(BLOCK), 0, stream>>>(P);
  k_cross<<<dim3(480), dim3(BLOCK), 0, stream>>>(P);
}

// Round 4
// 477.437 us; speedup vs baseline: 1.5498x; 1.5498x over previous
//
#include <hip/hip_runtime.h>
#include <math.h>

// PointPWC multi-scale loss. B=2, scales N={8192,4096,2048,1024}.
// Inputs (B,3,N) fp32 channel-major: pc1_0..3, pc2_0..3, flow_0..3.
// Output: single fp32 scalar.
//
// R4: index packed into low 13 mantissa bits of the squared distance ->
// branchless med3 top-k carries indices for free. Scan = 22 instr/cand,
// no LDS, no divergence, no compaction (R3's compact storm was ~40
// instr/cand). Epilogue re-gathers the K winners and recomputes exact
// distances (sums/weights are order-independent; only 9-vs-10 selection
// in pass B needs a max-drop).

#define QPB 64
#define NSLICE 8
#define BLOCK 512
#define NTOT 15360   // 8192+4096+2048+1024
#define SMWORDS (NSLICE * QPB * 11)   // key staging (stride 11, K<=10)

typedef unsigned int uint;

struct Params {
  const float* pc1[4];
  const float* pc2[4];
  const float* fl[4];
  float4* cv2;   // [B][NTOT]
  float4* cvw;   // [B][NTOT]
  float* out;
};

__device__ __forceinline__ void map_block(int r, int& s, int& b, int& i0,
                                          int& N, int& off, float& alpha) {
  if (r < 256)      { s = 0; }
  else if (r < 384) { s = 1; r -= 256; }
  else if (r < 448) { s = 2; r -= 384; }
  else              { s = 3; r -= 448; }
  int lg = 7 - s;
  b = r >> lg;
  i0 = (r & ((1 << lg) - 1)) * QPB;
  N = 8192 >> s;
  off = 16384 - (16384 >> s);   // {0, 8192, 12288, 14336}
  alpha = 0.02f * (float)(1 << s);
}

__device__ __forceinline__ float wave_sum(float v) {
  #pragma unroll
  for (int o = 32; o; o >>= 1) v += __shfl_down(v, o, 64);
  return v;
}

__device__ __forceinline__ float rlane(float v, int t) {
  return __int_as_float(__builtin_amdgcn_readlane(__float_as_int(v), t));
}

// Branchless insert of key kf into sorted-ascending kd[K].
template <int K>
__device__ __forceinline__ void key_insert(float (&kd)[K], float kf) {
  #pragma unroll
  for (int m = K - 1; m >= 1; --m)
    kd[m] = __builtin_amdgcn_fmed3f(kf, kd[m - 1], kd[m]);
  kd[0] = fminf(kd[0], kf);
}

// Scan candidate slice [lo,hi) (one query per thread). Keys carry indices
// in the low 13 bits; top-K keys end up sorted in kd[].
template <int K>
__device__ void scan_keys(const float* px, const float* py, const float* pz,
                          int lo, int hi, float ax, float ay, float az,
                          float (&kd)[K]) {
  int lane = threadIdx.x & 63;
  float cx = px[lo + lane], cy = py[lo + lane], cz = pz[lo + lane];
  for (int c0 = lo; c0 < hi; c0 += 64) {
    float nx = 0.f, ny = 0.f, nz = 0.f;
    if (c0 + 64 < hi) {
      nx = px[c0 + 64 + lane]; ny = py[c0 + 64 + lane];
      nz = pz[c0 + 64 + lane];
    }
    #pragma unroll 8
    for (int t = 0; t < 64; ++t) {
      float sx = rlane(cx, t), sy = rlane(cy, t), sz = rlane(cz, t);
      float dx = ax - sx, dy = ay - sy, dz = az - sz;
      float d = fmaf(dx, dx, fmaf(dy, dy, dz * dz));
      uint key = (__float_as_uint(d) & 0xFFFFE000u) + (uint)(c0 + t);
      key_insert<K>(kd, __uint_as_float(key));
    }
    cx = nx; cy = ny; cz = nz;
  }
}

// Stage per-wave keys to LDS; wave 0 merges all 8 slices for its query.
template <int K>
__device__ bool merge_block(float (&kd)[K], float* sm, int tid) {
  int q = tid & 63, wv = tid >> 6;
  const int STR = (K & 1) ? K : K + 1;   // odd stride -> bank-friendly
  #pragma unroll
  for (int m = 0; m < K; ++m) sm[(wv * 64 + q) * STR + m] = kd[m];
  __syncthreads();
  if (wv) return false;
  for (int w = 1; w < NSLICE; ++w)
    #pragma unroll
    for (int m = 0; m < K; ++m)
      key_insert<K>(kd, sm[(w * 64 + q) * STR + m]);
  return true;
}

__global__ __launch_bounds__(1) void k_zero(float* out) { out[0] = 0.f; }

// pass 0 (A): self-KNN p2 k=10 -> cv2
// pass 1 (B): self-KNN p1 k=10 -> cvw + smoothness
// pass 2 (D): p2 -> warp min (dist2)
__global__ __launch_bounds__(BLOCK) void k_fused(Params P) {
  __shared__ float sm[SMWORDS];
  int tid = threadIdx.x;
  int q = tid & 63, wv = tid >> 6;
  int pass = blockIdx.x / 480;
  int r = blockIdx.x % 480;
  int s, b, i0, N, off; float alpha;
  map_block(r, s, b, i0, N, off, alpha);
  int sl = N / NSLICE;
  int lo = wv * sl, hi = lo + sl;
  int i = i0 + q;

  if (pass == 0) {
    const float* p2 = P.pc2[s] + b * 3 * N;
    float ax = p2[i], ay = p2[N + i], az = p2[2 * N + i];
    float kd[10];
    #pragma unroll
    for (int m = 0; m < 10; ++m) kd[m] = 3.0e38f;
    scan_keys<10>(p2, p2 + N, p2 + 2 * N, lo, hi, ax, ay, az, kd);
    if (!merge_block<10>(kd, sm, tid)) return;
    float sx = 0.f, sy = 0.f, sz = 0.f;
    #pragma unroll
    for (int m = 0; m < 10; ++m) {
      int j = (int)(__float_as_uint(kd[m]) & 0x1FFFu);
      sx += p2[j]; sy += p2[N + j]; sz += p2[2 * N + j];
    }
    const float inv9 = 1.f / 9.f;
    P.cv2[b * NTOT + off + i] = make_float4((sx - 10.f * ax) * inv9,
                                            (sy - 10.f * ay) * inv9,
                                            (sz - 10.f * az) * inv9, 0.f);
  } else if (pass == 1) {
    const float* p1 = P.pc1[s] + b * 3 * N;
    const float* fl = P.fl[s] + b * 3 * N;
    float ax = p1[i], ay = p1[N + i], az = p1[2 * N + i];
    float kd[10];
    #pragma unroll
    for (int m = 0; m < 10; ++m) kd[m] = 3.0e38f;
    scan_keys<10>(p1, p1 + N, p1 + 2 * N, lo, hi, ax, ay, az, kd);
    if (!merge_block<10>(kd, sm, tid)) return;
    float fix = fl[i], fiy = fl[N + i], fiz = fl[2 * N + i];
    float wix = ax + fix, wiy = ay + fiy, wiz = az + fiz;
    float sx = 0.f, sy = 0.f, sz = 0.f, smooth = 0.f;
    float dmax = -1.f, worst = 0.f;
    #pragma unroll
    for (int m = 0; m < 10; ++m) {
      int j = (int)(__float_as_uint(kd[m]) & 0x1FFFu);
      float px = p1[j], py = p1[N + j], pz = p1[2 * N + j];
      float flx = fl[j], fly = fl[N + j], flz = fl[2 * N + j];
      sx += px + flx; sy += py + fly; sz += pz + flz;
      float ddx = px - ax, ddy = py - ay, ddz = pz - az;
      float d = fmaf(ddx, ddx, fmaf(ddy, ddy, ddz * ddz));  // exact
      float gx = flx - fix, gy = fly - fiy, gz = flz - fiz;
      float term = sqrtf(fmaf(gx, gx, fmaf(gy, gy, gz * gz)));
      smooth += term;
      if (d > dmax) { dmax = d; worst = term; }  // drop farthest (k9 of k10)
    }
    smooth -= worst;
    const float inv9 = 1.f / 9.f;
    P.cvw[b * NTOT + off + i] = make_float4((sx - 10.f * wix) * inv9,
                                            (sy - 10.f * wiy) * inv9,
                                            (sz - 10.f * wiz) * inv9, 0.f);
    float ssum = wave_sum(smooth * (1.f / 8.f));
    if (q == 0) atomicAdd(P.out, alpha * 0.5f * ssum);
  } else {
    const float* p1 = P.pc1[s] + b * 3 * N;
    const float* fl = P.fl[s] + b * 3 * N;
    const float* p2 = P.pc2[s] + b * 3 * N;
    float ax = p2[i], ay = p2[N + i], az = p2[2 * N + i];
    float cx = p1[lo + q] + fl[lo + q];
    float cy = p1[N + lo + q] + fl[N + lo + q];
    float cz = p1[2 * N + lo + q] + fl[2 * N + lo + q];
    float dmin = 3.0e38f;
    for (int c0 = lo; c0 < hi; c0 += 64) {
      float nx = 0.f, ny = 0.f, nz = 0.f;
      if (c0 + 64 < hi) {
        int j = c0 + 64 + q;
        nx = p1[j] + fl[j];
        ny = p1[N + j] + fl[N + j];
        nz = p1[2 * N + j] + fl[2 * N + j];
      }
      #pragma unroll 8
      for (int t = 0; t < 64; ++t) {
        float sx = rlane(cx, t), sy = rlane(cy, t), sz = rlane(cz, t);
        float dx = ax - sx, dy = ay - sy, dz = az - sz;
        dmin = fminf(dmin, fmaf(dx, dx, fmaf(dy, dy, dz * dz)));
      }
      cx = nx; cy = ny; cz = nz;
    }
    sm[tid] = dmin;
    __syncthreads();
    if (wv) return;
    #pragma unroll
    for (int w = 1; w < NSLICE; ++w) dmin = fminf(dmin, sm[w * 64 + q]);
    float msum = wave_sum(dmin);
    if (q == 0) atomicAdd(P.out, alpha * 0.5f * msum);
  }
}

// Pass C: warp -> p2 top-5: dist1 + inverse-distance cv2 interp -> curvature
__global__ __launch_bounds__(BLOCK) void k_cross(Params P) {
  __shared__ float sm[SMWORDS];
  int tid = threadIdx.x;
  int q = tid & 63;
  int s, b, i0, N, off; float alpha;
  map_block(blockIdx.x, s, b, i0, N, off, alpha);
  int sl = N / NSLICE;
  int wv = tid >> 6;
  int lo = wv * sl, hi = lo + sl;
  int i = i0 + q;
  const float* p1 = P.pc1[s] + b * 3 * N;
  const float* fl = P.fl[s] + b * 3 * N;
  const float* p2 = P.pc2[s] + b * 3 * N;
  float ax = p1[i] + fl[i], ay = p1[N + i] + fl[N + i],
        az = p1[2 * N + i] + fl[2 * N + i];
  float kd[5];
  #pragma unroll
  for (int m = 0; m < 5; ++m) kd[m] = 3.0e38f;
  scan_keys<5>(p2, p2 + N, p2 + 2 * N, lo, hi, ax, ay, az, kd);
  if (!merge_block<5>(kd, sm, tid)) return;
  float dist1 = 3.0e38f, wsum = 0.f, ix = 0.f, iy = 0.f, iz = 0.f;
  #pragma unroll
  for (int m = 0; m < 5; ++m) {
    int j = (int)(__float_as_uint(kd[m]) & 0x1FFFu);
    float px = p2[j], py = p2[N + j], pz = p2[2 * N + j];
    float ddx = px - ax, ddy = py - ay, ddz = pz - az;
    float d = fmaf(ddx, ddx, fmaf(ddy, ddy, ddz * ddz));  // exact
    dist1 = fminf(dist1, d);
    float w = 1.f / (d + 1e-8f);
    wsum += w;
    float4 cv = P.cv2[b * NTOT + off + j];
    ix += w * cv.x; iy += w * cv.y; iz += w * cv.z;
  }
  float inv = 1.f / wsum;
  ix *= inv; iy *= inv; iz *= inv;
  float4 cw = P.cvw[b * NTOT + off + i];
  float ex = ix - cw.x, ey = iy - cw.y, ez = iz - cw.z;
  float curv = fmaf(ex, ex, fmaf(ey, ey, ez * ez));
  float csum = wave_sum(dist1 + 0.3f * curv);
  if (q == 0) atomicAdd(P.out, alpha * 0.5f * csum);
}

extern "C" void kernel_launch(void* const* d_in, const int* in_sizes, int n_in,
                              void* d_out, int out_size, void* d_ws,
                              size_t ws_size, hipStream_t stream) {
  Params P;
  for (int s = 0; s < 4; ++s) {
    P.pc1[s] = (const float*)d_in[s];
    P.pc2[s] = (const float*)d_in[4 + s];
    P.fl[s]  = (const float*)d_in[8 + s];
  }
  P.cv2 = (float4*)d_ws;
  P.cvw = (float4*)((char*)d_ws + (size_t)2 * NTOT * sizeof(float4));
  P.out = (float*)d_out;

  k_zero<<<dim3(1), dim3(1), 0, stream>>>(P.out);
  k_fused<<<dim3(1440), dim3(BLOCK), 0, stream>>>(P);
  k_cross<<<dim3(480), dim3(BLOCK), 0, stream>>>(P);
}

// Round 5
// 399.656 us; speedup vs baseline: 1.8514x; 1.1946x over previous
//
#include <hip/hip_runtime.h>
#include <math.h>

// PointPWC multi-scale loss. B=2, scales N={8192,4096,2048,1024}.
// Inputs (B,3,N) fp32 channel-major: pc1_0..3, pc2_0..3, flow_0..3.
// Output: single fp32 scalar.
//
// R5: candidate broadcast via wave-uniform ds_read_b128 from a per-wave
// 64-candidate LDS tile (LDS pipe, zero VALU addressing, broadcast =
// conflict-free) instead of v_readlane (VALU instr + SGPR-write hazard).
// Index pre-packed in float4.w -> key pack is one all-VGPR v_and_or_b32.
// Nominal VALU/cand: A/B 17, C 12, D 7 (was 21/16/10).

#define QPB 64
#define NSLICE 8
#define BLOCK 512
#define NTOT 15360   // 8192+4096+2048+1024
#define MASKC 0xFFFFE000u

typedef unsigned int uint;

struct Params {
  const float* pc1[4];
  const float* pc2[4];
  const float* fl[4];
  float4* cv2;   // [B][NTOT]
  float4* cvw;   // [B][NTOT]
  float* out;
};

__device__ __forceinline__ void map_block(int r, int& s, int& b, int& i0,
                                          int& N, int& off, float& alpha) {
  if (r < 256)      { s = 0; }
  else if (r < 384) { s = 1; r -= 256; }
  else if (r < 448) { s = 2; r -= 384; }
  else              { s = 3; r -= 448; }
  int lg = 7 - s;
  b = r >> lg;
  i0 = (r & ((1 << lg) - 1)) * QPB;
  N = 8192 >> s;
  off = 16384 - (16384 >> s);   // {0, 8192, 12288, 14336}
  alpha = 0.02f * (float)(1 << s);
}

__device__ __forceinline__ float wave_sum(float v) {
  #pragma unroll
  for (int o = 32; o; o >>= 1) v += __shfl_down(v, o, 64);
  return v;
}

// Branchless insert of key kf into sorted-ascending kd[K].
template <int K>
__device__ __forceinline__ void key_insert(float (&kd)[K], float kf) {
  #pragma unroll
  for (int m = K - 1; m >= 1; --m)
    kd[m] = __builtin_amdgcn_fmed3f(kf, kd[m - 1], kd[m]);
  kd[0] = fminf(kd[0], kf);
}

// Scan candidate slice [lo,hi) (one query per thread). Candidates staged
// 64 at a time into this wave's private LDS tile; inner reads are at
// wave-uniform addresses (broadcast, conflict-free, imm offsets).
// PACK: carry candidate index in low 13 key bits (top-k passes).
// !PACK: raw distances (exact min, pass D).
template <int K, bool WARP, bool PACK>
__device__ void scan_tile(const float* px, const float* py, const float* pz,
                          const float* fx, const float* fy, const float* fz,
                          int lo, int hi, float ax, float ay, float az,
                          float (&kd)[K], float4* tile, int lane) {
  for (int c0 = lo; c0 < hi; c0 += 64) {
    int j = c0 + lane;
    float x = px[j], y = py[j], z = pz[j];
    if (WARP) { x += fx[j]; y += fy[j]; z += fz[j]; }
    float4 v;
    v.x = x; v.y = y; v.z = z; v.w = __uint_as_float((uint)j);
    tile[lane] = v;
    // fill-write -> broadcast-read is same-wave: DS pipe is in-order per
    // wave; just drain outstanding LDS ops (no block barrier needed).
    asm volatile("s_waitcnt lgkmcnt(0)" ::: "memory");
    #pragma unroll 16
    for (int t = 0; t < 64; ++t) {
      float4 c = tile[t];              // wave-uniform addr -> broadcast
      float dx = ax - c.x, dy = ay - c.y, dz = az - c.z;
      float d = fmaf(dx, dx, fmaf(dy, dy, dz * dz));
      if (PACK) {
        uint key = (__float_as_uint(d) & MASKC) | __float_as_uint(c.w);
        key_insert<K>(kd, __uint_as_float(key));
      } else {
        key_insert<K>(kd, d);
      }
    }
    asm volatile("" ::: "memory");
  }
}

// Stage per-wave keys to LDS; wave 0 merges all 8 slices for its query.
template <int K>
__device__ bool merge_block(float (&kd)[K], float* sm, int tid) {
  int q = tid & 63, wv = tid >> 6;
  const int STR = (K & 1) ? K : K + 1;   // odd stride -> bank-friendly
  #pragma unroll
  for (int m = 0; m < K; ++m) sm[(wv * 64 + q) * STR + m] = kd[m];
  __syncthreads();
  if (wv) return false;
  for (int w = 1; w < NSLICE; ++w)
    #pragma unroll
    for (int m = 0; m < K; ++m)
      key_insert<K>(kd, sm[(w * 64 + q) * STR + m]);
  return true;
}

__global__ __launch_bounds__(1) void k_zero(float* out) { out[0] = 0.f; }

// pass 0 (A): self-KNN p2 k=10 -> cv2
// pass 1 (B): self-KNN p1 k=10 -> cvw + smoothness
// pass 2 (D): p2 -> warp min (dist2)
__global__ __launch_bounds__(BLOCK) void k_fused(Params P) {
  __shared__ float4 tiles[NSLICE][64];        // 8 KB
  __shared__ float sm[NSLICE * QPB * 11];     // 22.5 KB (merge staging)
  int tid = threadIdx.x;
  int q = tid & 63, wv = tid >> 6;
  int pass = blockIdx.x / 480;
  int r = blockIdx.x % 480;
  int s, b, i0, N, off; float alpha;
  map_block(r, s, b, i0, N, off, alpha);
  int sl = N / NSLICE;
  int lo = wv * sl, hi = lo + sl;
  int i = i0 + q;
  float4* tile = tiles[wv];

  if (pass == 0) {
    const float* p2 = P.pc2[s] + b * 3 * N;
    float ax = p2[i], ay = p2[N + i], az = p2[2 * N + i];
    float kd[10];
    #pragma unroll
    for (int m = 0; m < 10; ++m) kd[m] = 3.0e38f;
    scan_tile<10, false, true>(p2, p2 + N, p2 + 2 * N, nullptr, nullptr,
                               nullptr, lo, hi, ax, ay, az, kd, tile, q);
    if (!merge_block<10>(kd, sm, tid)) return;
    float sx = 0.f, sy = 0.f, sz = 0.f;
    #pragma unroll
    for (int m = 0; m < 10; ++m) {
      int j = (int)(__float_as_uint(kd[m]) & 0x1FFFu);
      sx += p2[j]; sy += p2[N + j]; sz += p2[2 * N + j];
    }
    const float inv9 = 1.f / 9.f;
    P.cv2[b * NTOT + off + i] = make_float4((sx - 10.f * ax) * inv9,
                                            (sy - 10.f * ay) * inv9,
                                            (sz - 10.f * az) * inv9, 0.f);
  } else if (pass == 1) {
    const float* p1 = P.pc1[s] + b * 3 * N;
    const float* fl = P.fl[s] + b * 3 * N;
    float ax = p1[i], ay = p1[N + i], az = p1[2 * N + i];
    float kd[10];
    #pragma unroll
    for (int m = 0; m < 10; ++m) kd[m] = 3.0e38f;
    scan_tile<10, false, true>(p1, p1 + N, p1 + 2 * N, nullptr, nullptr,
                               nullptr, lo, hi, ax, ay, az, kd, tile, q);
    if (!merge_block<10>(kd, sm, tid)) return;
    float fix = fl[i], fiy = fl[N + i], fiz = fl[2 * N + i];
    float wix = ax + fix, wiy = ay + fiy, wiz = az + fiz;
    float sx = 0.f, sy = 0.f, sz = 0.f, smooth = 0.f;
    float dmax = -1.f, worst = 0.f;
    #pragma unroll
    for (int m = 0; m < 10; ++m) {
      int j = (int)(__float_as_uint(kd[m]) & 0x1FFFu);
      float px = p1[j], py = p1[N + j], pz = p1[2 * N + j];
      float flx = fl[j], fly = fl[N + j], flz = fl[2 * N + j];
      sx += px + flx; sy += py + fly; sz += pz + flz;
      float ddx = px - ax, ddy = py - ay, ddz = pz - az;
      float d = fmaf(ddx, ddx, fmaf(ddy, ddy, ddz * ddz));  // exact
      float gx = flx - fix, gy = fly - fiy, gz = flz - fiz;
      float term = sqrtf(fmaf(gx, gx, fmaf(gy, gy, gz * gz)));
      smooth += term;
      if (d > dmax) { dmax = d; worst = term; }  // drop farthest (k9 of k10)
    }
    smooth -= worst;
    const float inv9 = 1.f / 9.f;
    P.cvw[b * NTOT + off + i] = make_float4((sx - 10.f * wix) * inv9,
                                            (sy - 10.f * wiy) * inv9,
                                            (sz - 10.f * wiz) * inv9, 0.f);
    float ssum = wave_sum(smooth * (1.f / 8.f));
    if (q == 0) atomicAdd(P.out, alpha * 0.5f * ssum);
  } else {
    const float* p1 = P.pc1[s] + b * 3 * N;
    const float* fl = P.fl[s] + b * 3 * N;
    const float* p2 = P.pc2[s] + b * 3 * N;
    float ax = p2[i], ay = p2[N + i], az = p2[2 * N + i];
    float kd[1];
    kd[0] = 3.0e38f;
    scan_tile<1, true, false>(p1, p1 + N, p1 + 2 * N, fl, fl + N, fl + 2 * N,
                              lo, hi, ax, ay, az, kd, tile, q);
    sm[tid] = kd[0];
    __syncthreads();
    if (wv) return;
    float dmin = kd[0];
    #pragma unroll
    for (int w = 1; w < NSLICE; ++w) dmin = fminf(dmin, sm[w * 64 + q]);
    float msum = wave_sum(dmin);
    if (q == 0) atomicAdd(P.out, alpha * 0.5f * msum);
  }
}

// Pass C: warp -> p2 top-5: dist1 + inverse-distance cv2 interp -> curvature
__global__ __launch_bounds__(BLOCK) void k_cross(Params P) {
  __shared__ float4 tiles[NSLICE][64];
  __shared__ float sm[NSLICE * QPB * 11];
  int tid = threadIdx.x;
  int q = tid & 63, wv = tid >> 6;
  int s, b, i0, N, off; float alpha;
  map_block(blockIdx.x, s, b, i0, N, off, alpha);
  int sl = N / NSLICE;
  int lo = wv * sl, hi = lo + sl;
  int i = i0 + q;
  const float* p1 = P.pc1[s] + b * 3 * N;
  const float* fl = P.fl[s] + b * 3 * N;
  const float* p2 = P.pc2[s] + b * 3 * N;
  float ax = p1[i] + fl[i], ay = p1[N + i] + fl[N + i],
        az = p1[2 * N + i] + fl[2 * N + i];
  float kd[5];
  #pragma unroll
  for (int m = 0; m < 5; ++m) kd[m] = 3.0e38f;
  scan_tile<5, false, true>(p2, p2 + N, p2 + 2 * N, nullptr, nullptr,
                            nullptr, lo, hi, ax, ay, az, kd, tiles[wv], q);
  if (!merge_block<5>(kd, sm, tid)) return;
  float dist1 = 3.0e38f, wsum = 0.f, ix = 0.f, iy = 0.f, iz = 0.f;
  #pragma unroll
  for (int m = 0; m < 5; ++m) {
    int j = (int)(__float_as_uint(kd[m]) & 0x1FFFu);
    float px = p2[j], py = p2[N + j], pz = p2[2 * N + j];
    float ddx = px - ax, ddy = py - ay, ddz = pz - az;
    float d = fmaf(ddx, ddx, fmaf(ddy, ddy, ddz * ddz));  // exact
    dist1 = fminf(dist1, d);
    float w = 1.f / (d + 1e-8f);
    wsum += w;
    float4 cv = P.cv2[b * NTOT + off + j];
    ix += w * cv.x; iy += w * cv.y; iz += w * cv.z;
  }
  float inv = 1.f / wsum;
  ix *= inv; iy *= inv; iz *= inv;
  float4 cw = P.cvw[b * NTOT + off + i];
  float ex = ix - cw.x, ey = iy - cw.y, ez = iz - cw.z;
  float curv = fmaf(ex, ex, fmaf(ey, ey, ez * ez));
  float csum = wave_sum(dist1 + 0.3f * curv);
  if (q == 0) atomicAdd(P.out, alpha * 0.5f * csum);
}

extern "C" void kernel_launch(void* const* d_in, const int* in_sizes, int n_in,
                              void* d_out, int out_size, void* d_ws,
                              size_t ws_size, hipStream_t stream) {
  Params P;
  for (int s = 0; s < 4; ++s) {
    P.pc1[s] = (const float*)d_in[s];
    P.pc2[s] = (const float*)d_in[4 + s];
    P.fl[s]  = (const float*)d_in[8 + s];
  }
  P.cv2 = (float4*)d_ws;
  P.cvw = (float4*)((char*)d_ws + (size_t)2 * NTOT * sizeof(float4));
  P.out = (float*)d_out;

  k_zero<<<dim3(1), dim3(1), 0, stream>>>(P.out);
  k_fused<<<dim3(1440), dim3(BLOCK), 0, stream>>>(P);
  k_cross<<<dim3(480), dim3(BLOCK), 0, stream>>>(P);
}

// Round 6
// 388.408 us; speedup vs baseline: 1.9050x; 1.0290x over previous
//
#include <hip/hip_runtime.h>
#include <math.h>

// PointPWC multi-scale loss. B=2, scales N={8192,4096,2048,1024}.
// Inputs (B,3,N) fp32 channel-major: pc1_0..3, pc2_0..3, flow_0..3.
// Output: single fp32 scalar.
//
// R6: 2 queries per thread. One ds_read_b128 broadcast feeds two
// independent dist+med3 chains -> fills the lgkm-stall windows that
// limited R4/R5 (real VALU busy was ~45%; rocprof's VALUBusy uses the
// gfx94x 4-cyc formula and reads ~2x high). Iterations halve; broadcast
// and loop overhead amortize over 2 pairs. Global prefetch of next tile
// rides the vmcnt leash across 64 inner iterations.

#define NSLICE 8
#define BLOCK 512
#define NTOT 15360   // 8192+4096+2048+1024
#define MASKC 0xFFFFE000u

typedef unsigned int uint;

struct Params {
  const float* pc1[4];
  const float* pc2[4];
  const float* fl[4];
  float4* cv2;   // [B][NTOT]
  float4* cvw;   // [B][NTOT]
  float* out;
};

// 240 blocks per pass: 128 queries (2 halves of 64) per block.
__device__ __forceinline__ void map_block2(int r, int& s, int& b, int& i0,
                                           int& N, int& off, float& alpha) {
  if (r < 128)      { s = 0; }
  else if (r < 192) { s = 1; r -= 128; }
  else if (r < 224) { s = 2; r -= 192; }
  else              { s = 3; r -= 224; }
  int lg = 6 - s;                 // log2(N/128)
  b = r >> lg;
  i0 = (r & ((1 << lg) - 1)) * 128;
  N = 8192 >> s;
  off = 16384 - (16384 >> s);     // {0, 8192, 12288, 14336}
  alpha = 0.02f * (float)(1 << s);
}

__device__ __forceinline__ float wave_sum(float v) {
  #pragma unroll
  for (int o = 32; o; o >>= 1) v += __shfl_down(v, o, 64);
  return v;
}

// Branchless insert of key kf into sorted-ascending kd[K].
template <int K>
__device__ __forceinline__ void key_insert(float (&kd)[K], float kf) {
  #pragma unroll
  for (int m = K - 1; m >= 1; --m)
    kd[m] = __builtin_amdgcn_fmed3f(kf, kd[m - 1], kd[m]);
  kd[0] = fminf(kd[0], kf);
}

// Scan slice [lo,hi): two queries per thread, candidates broadcast from a
// per-wave LDS tile (wave-uniform ds_read_b128). PACK: idx in low 13 bits.
template <int K, bool WARP, bool PACK>
__device__ void scan2(const float* px, const float* py, const float* pz,
                      const float* fx, const float* fy, const float* fz,
                      int lo, int hi,
                      float ax0, float ay0, float az0,
                      float ax1, float ay1, float az1,
                      float (&kd0)[K], float (&kd1)[K],
                      float4* tile, int lane) {
  int j = lo + lane;
  float x = px[j], y = py[j], z = pz[j];
  if (WARP) { x += fx[j]; y += fy[j]; z += fz[j]; }
  for (int c0 = lo; c0 < hi; c0 += 64) {
    tile[lane] = make_float4(x, y, z, __uint_as_float((uint)(c0 + lane)));
    // same-wave fill->broadcast: DS pipe in-order; no block barrier needed
    asm volatile("s_waitcnt lgkmcnt(0)" ::: "memory");
    if (c0 + 64 < hi) {           // prefetch next tile (vmcnt leash)
      int jn = j + 64;
      x = px[jn]; y = py[jn]; z = pz[jn];
      if (WARP) { x += fx[jn]; y += fy[jn]; z += fz[jn]; }
    }
    #pragma unroll 16
    for (int t = 0; t < 64; ++t) {
      float4 c = tile[t];          // wave-uniform addr -> broadcast
      float dx0 = ax0 - c.x, dy0 = ay0 - c.y, dz0 = az0 - c.z;
      float d0 = fmaf(dx0, dx0, fmaf(dy0, dy0, dz0 * dz0));
      float dx1 = ax1 - c.x, dy1 = ay1 - c.y, dz1 = az1 - c.z;
      float d1 = fmaf(dx1, dx1, fmaf(dy1, dy1, dz1 * dz1));
      if (PACK) {
        uint iw = __float_as_uint(c.w);
        key_insert<K>(kd0,
            __uint_as_float((__float_as_uint(d0) & MASKC) | iw));
        key_insert<K>(kd1,
            __uint_as_float((__float_as_uint(d1) & MASKC) | iw));
      } else {
        kd0[0] = fminf(kd0[0], d0);
        kd1[0] = fminf(kd1[0], d1);
      }
    }
    j += 64;
  }
}

// Stage both per-thread lists to LDS; wave 0 finalizes query-half 0 into
// kd0, wave 1 finalizes half 1 into kd1. Returns half id, or -1 (done).
template <int K>
__device__ int merge2(float (&kd0)[K], float (&kd1)[K], float* sm, int tid) {
  const int STR = K | 1;          // odd stride -> conflict-free
  int q = tid & 63, wv = tid >> 6;
  #pragma unroll
  for (int m = 0; m < K; ++m) {
    sm[(wv * 128 + q) * STR + m] = kd0[m];
    sm[(wv * 128 + 64 + q) * STR + m] = kd1[m];
  }
  __syncthreads();
  if (wv == 0) {
    for (int w = 1; w < NSLICE; ++w)
      #pragma unroll
      for (int m = 0; m < K; ++m)
        key_insert<K>(kd0, sm[(w * 128 + q) * STR + m]);
    return 0;
  }
  if (wv == 1) {
    for (int w = 0; w < NSLICE; ++w) {
      if (w == 1) continue;
      #pragma unroll
      for (int m = 0; m < K; ++m)
        key_insert<K>(kd1, sm[(w * 128 + 64 + q) * STR + m]);
    }
    return 1;
  }
  return -1;
}

__global__ __launch_bounds__(1) void k_zero(float* out) { out[0] = 0.f; }

// pass 0 (A): self-KNN p2 k=10 -> cv2
// pass 1 (B): self-KNN p1 k=10 -> cvw + smoothness
// pass 2 (D): p2 -> warp min (dist2)
__global__ __launch_bounds__(BLOCK) void k_fused(Params P) {
  __shared__ float4 tiles[NSLICE][64];          // 8 KB
  __shared__ float sm[NSLICE * 128 * 11];       // 44 KB
  int tid = threadIdx.x, q = tid & 63, wv = tid >> 6;
  int pass = blockIdx.x / 240, r = blockIdx.x % 240;
  int s, b, i0, N, off; float alpha;
  map_block2(r, s, b, i0, N, off, alpha);
  int sl = N / NSLICE, lo = wv * sl, hi = lo + sl;
  int iA = i0 + q, iB = i0 + 64 + q;
  float4* tile = tiles[wv];

  if (pass == 0) {
    const float* p2 = P.pc2[s] + b * 3 * N;
    float ax0 = p2[iA], ay0 = p2[N + iA], az0 = p2[2 * N + iA];
    float ax1 = p2[iB], ay1 = p2[N + iB], az1 = p2[2 * N + iB];
    float kd0[10], kd1[10];
    #pragma unroll
    for (int m = 0; m < 10; ++m) { kd0[m] = 3.0e38f; kd1[m] = 3.0e38f; }
    scan2<10, false, true>(p2, p2 + N, p2 + 2 * N, nullptr, nullptr, nullptr,
                           lo, hi, ax0, ay0, az0, ax1, ay1, az1, kd0, kd1,
                           tile, q);
    int half = merge2<10>(kd0, kd1, sm, tid);
    if (half < 0) return;
    const float* kd = half ? kd1 : kd0;
    int i = half ? iB : iA;
    float ax = half ? ax1 : ax0, ay = half ? ay1 : ay0,
          az = half ? az1 : az0;
    float sx = 0.f, sy = 0.f, sz = 0.f;
    #pragma unroll
    for (int m = 0; m < 10; ++m) {
      int j = (int)(__float_as_uint(kd[m]) & 0x1FFFu);
      sx += p2[j]; sy += p2[N + j]; sz += p2[2 * N + j];
    }
    const float inv9 = 1.f / 9.f;
    P.cv2[b * NTOT + off + i] = make_float4((sx - 10.f * ax) * inv9,
                                            (sy - 10.f * ay) * inv9,
                                            (sz - 10.f * az) * inv9, 0.f);
  } else if (pass == 1) {
    const float* p1 = P.pc1[s] + b * 3 * N;
    const float* fl = P.fl[s] + b * 3 * N;
    float ax0 = p1[iA], ay0 = p1[N + iA], az0 = p1[2 * N + iA];
    float ax1 = p1[iB], ay1 = p1[N + iB], az1 = p1[2 * N + iB];
    float kd0[10], kd1[10];
    #pragma unroll
    for (int m = 0; m < 10; ++m) { kd0[m] = 3.0e38f; kd1[m] = 3.0e38f; }
    scan2<10, false, true>(p1, p1 + N, p1 + 2 * N, nullptr, nullptr, nullptr,
                           lo, hi, ax0, ay0, az0, ax1, ay1, az1, kd0, kd1,
                           tile, q);
    int half = merge2<10>(kd0, kd1, sm, tid);
    if (half < 0) return;
    const float* kd = half ? kd1 : kd0;
    int i = half ? iB : iA;
    float ax = half ? ax1 : ax0, ay = half ? ay1 : ay0,
          az = half ? az1 : az0;
    float fix = fl[i], fiy = fl[N + i], fiz = fl[2 * N + i];
    float wix = ax + fix, wiy = ay + fiy, wiz = az + fiz;
    float sx = 0.f, sy = 0.f, sz = 0.f, smooth = 0.f;
    float dmax = -1.f, worst = 0.f;
    #pragma unroll
    for (int m = 0; m < 10; ++m) {
      int j = (int)(__float_as_uint(kd[m]) & 0x1FFFu);
      float px = p1[j], py = p1[N + j], pz = p1[2 * N + j];
      float flx = fl[j], fly = fl[N + j], flz = fl[2 * N + j];
      sx += px + flx; sy += py + fly; sz += pz + flz;
      float ddx = px - ax, ddy = py - ay, ddz = pz - az;
      float d = fmaf(ddx, ddx, fmaf(ddy, ddy, ddz * ddz));  // exact
      float gx = flx - fix, gy = fly - fiy, gz = flz - fiz;
      float term = sqrtf(fmaf(gx, gx, fmaf(gy, gy, gz * gz)));
      smooth += term;
      if (d > dmax) { dmax = d; worst = term; }  // drop farthest (k9)
    }
    smooth -= worst;
    const float inv9 = 1.f / 9.f;
    P.cvw[b * NTOT + off + i] = make_float4((sx - 10.f * wix) * inv9,
                                            (sy - 10.f * wiy) * inv9,
                                            (sz - 10.f * wiz) * inv9, 0.f);
    float ssum = wave_sum(smooth * (1.f / 8.f));
    if (q == 0) atomicAdd(P.out, alpha * 0.5f * ssum);
  } else {
    const float* p1 = P.pc1[s] + b * 3 * N;
    const float* fl = P.fl[s] + b * 3 * N;
    const float* p2 = P.pc2[s] + b * 3 * N;
    float ax0 = p2[iA], ay0 = p2[N + iA], az0 = p2[2 * N + iA];
    float ax1 = p2[iB], ay1 = p2[N + iB], az1 = p2[2 * N + iB];
    float kd0[1], kd1[1];
    kd0[0] = 3.0e38f; kd1[0] = 3.0e38f;
    scan2<1, true, false>(p1, p1 + N, p1 + 2 * N, fl, fl + N, fl + 2 * N,
                          lo, hi, ax0, ay0, az0, ax1, ay1, az1, kd0, kd1,
                          tile, q);
    sm[wv * 128 + q] = kd0[0];
    sm[wv * 128 + 64 + q] = kd1[0];
    __syncthreads();
    if (wv >= 2) return;
    int base = (wv == 0) ? q : 64 + q;
    float dmin = 3.0e38f;
    #pragma unroll
    for (int w = 0; w < NSLICE; ++w)
      dmin = fminf(dmin, sm[w * 128 + base]);
    float msum = wave_sum(dmin);
    if (q == 0) atomicAdd(P.out, alpha * 0.5f * msum);
  }
}

// Pass C: warp -> p2 top-5: dist1 + inverse-distance cv2 interp -> curvature
__global__ __launch_bounds__(BLOCK) void k_cross(Params P) {
  __shared__ float4 tiles[NSLICE][64];
  __shared__ float sm[NSLICE * 128 * 5];
  int tid = threadIdx.x, q = tid & 63, wv = tid >> 6;
  int s, b, i0, N, off; float alpha;
  map_block2(blockIdx.x, s, b, i0, N, off, alpha);
  int sl = N / NSLICE, lo = wv * sl, hi = lo + sl;
  int iA = i0 + q, iB = i0 + 64 + q;
  const float* p1 = P.pc1[s] + b * 3 * N;
  const float* fl = P.fl[s] + b * 3 * N;
  const float* p2 = P.pc2[s] + b * 3 * N;
  float ax0 = p1[iA] + fl[iA], ay0 = p1[N + iA] + fl[N + iA],
        az0 = p1[2 * N + iA] + fl[2 * N + iA];
  float ax1 = p1[iB] + fl[iB], ay1 = p1[N + iB] + fl[N + iB],
        az1 = p1[2 * N + iB] + fl[2 * N + iB];
  float kd0[5], kd1[5];
  #pragma unroll
  for (int m = 0; m < 5; ++m) { kd0[m] = 3.0e38f; kd1[m] = 3.0e38f; }
  scan2<5, false, true>(p2, p2 + N, p2 + 2 * N, nullptr, nullptr, nullptr,
                        lo, hi, ax0, ay0, az0, ax1, ay1, az1, kd0, kd1,
                        tiles[wv], q);
  int half = merge2<5>(kd0, kd1, sm, tid);
  if (half < 0) return;
  const float* kd = half ? kd1 : kd0;
  int i = half ? iB : iA;
  float ax = half ? ax1 : ax0, ay = half ? ay1 : ay0, az = half ? az1 : az0;
  float dist1 = 3.0e38f, wsum = 0.f, ix = 0.f, iy = 0.f, iz = 0.f;
  #pragma unroll
  for (int m = 0; m < 5; ++m) {
    int j = (int)(__float_as_uint(kd[m]) & 0x1FFFu);
    float px = p2[j], py = p2[N + j], pz = p2[2 * N + j];
    float ddx = px - ax, ddy = py - ay, ddz = pz - az;
    float d = fmaf(ddx, ddx, fmaf(ddy, ddy, ddz * ddz));  // exact
    dist1 = fminf(dist1, d);
    float w = 1.f / (d + 1e-8f);
    wsum += w;
    float4 cv = P.cv2[b * NTOT + off + j];
    ix += w * cv.x; iy += w * cv.y; iz += w * cv.z;
  }
  float inv = 1.f / wsum;
  ix *= inv; iy *= inv; iz *= inv;
  float4 cw = P.cvw[b * NTOT + off + i];
  float ex = ix - cw.x, ey = iy - cw.y, ez = iz - cw.z;
  float curv = fmaf(ex, ex, fmaf(ey, ey, ez * ez));
  float csum = wave_sum(dist1 + 0.3f * curv);
  if (q == 0) atomicAdd(P.out, alpha * 0.5f * csum);
}

extern "C" void kernel_launch(void* const* d_in, const int* in_sizes, int n_in,
                              void* d_out, int out_size, void* d_ws,
                              size_t ws_size, hipStream_t stream) {
  Params P;
  for (int s = 0; s < 4; ++s) {
    P.pc1[s] = (const float*)d_in[s];
    P.pc2[s] = (const float*)d_in[4 + s];
    P.fl[s]  = (const float*)d_in[8 + s];
  }
  P.cv2 = (float4*)d_ws;
  P.cvw = (float4*)((char*)d_ws + (size_t)2 * NTOT * sizeof(float4));
  P.out = (float*)d_out;

  k_zero<<<dim3(1), dim3(1), 0, stream>>>(P.out);
  k_fused<<<dim3(720), dim3(BLOCK), 0, stream>>>(P);
  k_cross<<<dim3(240), dim3(BLOCK), 0, stream>>>(P);
}

// Round 7
// 358.758 us; speedup vs baseline: 2.0624x; 1.0826x over previous
//
#include <hip/hip_runtime.h>
#include <math.h>

// PointPWC multi-scale loss. B=2, scales N={8192,4096,2048,1024}.
// Inputs (B,3,N) fp32 channel-major: pc1_0..3, pc2_0..3, flow_0..3.
// Output: single fp32 scalar.
//
// R7: the R5/R6 stall is multiplicative (~2.2x issue) -> dependent-VALU
// latency (~4cyc) on the serial med3 insert chain. Fix: per query keep TWO
// alternating top-K chains (even/odd candidates; exact after per-thread
// merge) -> 2 queries x 2 chains = 4 independent chains per thread covers
// the latency shadow at 2-cyc issue without dropping block count.
// k_cross reverted to 480-block 1q/thread (R6's 240-block halving was a
// parallelism regression) + same dual-chain trick.

#define NSLICE 8
#define BLOCK 512
#define NTOT 15360   // 8192+4096+2048+1024
#define MASKC 0xFFFFE000u

typedef unsigned int uint;

struct Params {
  const float* pc1[4];
  const float* pc2[4];
  const float* fl[4];
  float4* cv2;   // [B][NTOT]
  float4* cvw;   // [B][NTOT]
  float* out;
};

// 480 blocks per pass: 64 queries per block (k_cross).
__device__ __forceinline__ void map_block(int r, int& s, int& b, int& i0,
                                          int& N, int& off, float& alpha) {
  if (r < 256)      { s = 0; }
  else if (r < 384) { s = 1; r -= 256; }
  else if (r < 448) { s = 2; r -= 384; }
  else              { s = 3; r -= 448; }
  int lg = 7 - s;
  b = r >> lg;
  i0 = (r & ((1 << lg) - 1)) * 64;
  N = 8192 >> s;
  off = 16384 - (16384 >> s);
  alpha = 0.02f * (float)(1 << s);
}

// 240 blocks per pass: 128 queries (2 halves of 64) per block (k_fused).
__device__ __forceinline__ void map_block2(int r, int& s, int& b, int& i0,
                                           int& N, int& off, float& alpha) {
  if (r < 128)      { s = 0; }
  else if (r < 192) { s = 1; r -= 128; }
  else if (r < 224) { s = 2; r -= 192; }
  else              { s = 3; r -= 224; }
  int lg = 6 - s;
  b = r >> lg;
  i0 = (r & ((1 << lg) - 1)) * 128;
  N = 8192 >> s;
  off = 16384 - (16384 >> s);
  alpha = 0.02f * (float)(1 << s);
}

__device__ __forceinline__ float wave_sum(float v) {
  #pragma unroll
  for (int o = 32; o; o >>= 1) v += __shfl_down(v, o, 64);
  return v;
}

// Branchless insert of key kf into sorted-ascending kd[K].
template <int K>
__device__ __forceinline__ void key_insert(float (&kd)[K], float kf) {
  #pragma unroll
  for (int m = K - 1; m >= 1; --m)
    kd[m] = __builtin_amdgcn_fmed3f(kf, kd[m - 1], kd[m]);
  kd[0] = fminf(kd[0], kf);
}

template <int K>
__device__ __forceinline__ void merge_pair(float (&a)[K], const float (&b)[K]) {
  #pragma unroll
  for (int m = 0; m < K; ++m) key_insert<K>(a, b[m]);
}

__device__ __forceinline__ float pack_key(float d, float iw) {
  return __uint_as_float((__float_as_uint(d) & MASKC) |
                         __float_as_uint(iw));
}

// 2 queries/thread, 2 chains/query (even/odd candidates). Candidates
// broadcast from this wave's private LDS tile (wave-uniform ds_read_b128).
template <int K, bool WARP, bool PACK>
__device__ void scan2d(const float* px, const float* py, const float* pz,
                       const float* fx, const float* fy, const float* fz,
                       int lo, int hi,
                       float ax0, float ay0, float az0,
                       float ax1, float ay1, float az1,
                       float (&a0)[K], float (&b0)[K],
                       float (&a1)[K], float (&b1)[K],
                       float4* tile, int lane) {
  int j = lo + lane;
  float x = px[j], y = py[j], z = pz[j];
  if (WARP) { x += fx[j]; y += fy[j]; z += fz[j]; }
  for (int c0 = lo; c0 < hi; c0 += 64) {
    tile[lane] = make_float4(x, y, z, __uint_as_float((uint)(c0 + lane)));
    // same-wave fill->broadcast: DS pipe is in-order per wave
    asm volatile("s_waitcnt lgkmcnt(0)" ::: "memory");
    if (c0 + 64 < hi) {   // prefetch next tile (rides vmcnt leash)
      int jn = j + 64;
      x = px[jn]; y = py[jn]; z = pz[jn];
      if (WARP) { x += fx[jn]; y += fy[jn]; z += fz[jn]; }
    }
    #pragma unroll 8
    for (int t = 0; t < 64; t += 2) {
      float4 cA = tile[t];
      float4 cB = tile[t + 1];
      float dxa0 = ax0 - cA.x, dya0 = ay0 - cA.y, dza0 = az0 - cA.z;
      float dA0 = fmaf(dxa0, dxa0, fmaf(dya0, dya0, dza0 * dza0));
      float dxb0 = ax0 - cB.x, dyb0 = ay0 - cB.y, dzb0 = az0 - cB.z;
      float dB0 = fmaf(dxb0, dxb0, fmaf(dyb0, dyb0, dzb0 * dzb0));
      float dxa1 = ax1 - cA.x, dya1 = ay1 - cA.y, dza1 = az1 - cA.z;
      float dA1 = fmaf(dxa1, dxa1, fmaf(dya1, dya1, dza1 * dza1));
      float dxb1 = ax1 - cB.x, dyb1 = ay1 - cB.y, dzb1 = az1 - cB.z;
      float dB1 = fmaf(dxb1, dxb1, fmaf(dyb1, dyb1, dzb1 * dzb1));
      if (PACK) {
        key_insert<K>(a0, pack_key(dA0, cA.w));
        key_insert<K>(b0, pack_key(dB0, cB.w));
        key_insert<K>(a1, pack_key(dA1, cA.w));
        key_insert<K>(b1, pack_key(dB1, cB.w));
      } else {
        a0[0] = fminf(a0[0], dA0);
        b0[0] = fminf(b0[0], dB0);
        a1[0] = fminf(a1[0], dA1);
        b1[0] = fminf(b1[0], dB1);
      }
    }
    j += 64;
  }
}

// 1 query/thread, 2 chains (k_cross).
template <int K>
__device__ void scan1d(const float* px, const float* py, const float* pz,
                       int lo, int hi, float ax, float ay, float az,
                       float (&a)[K], float (&b)[K], float4* tile,
                       int lane) {
  int j = lo + lane;
  float x = px[j], y = py[j], z = pz[j];
  for (int c0 = lo; c0 < hi; c0 += 64) {
    tile[lane] = make_float4(x, y, z, __uint_as_float((uint)(c0 + lane)));
    asm volatile("s_waitcnt lgkmcnt(0)" ::: "memory");
    if (c0 + 64 < hi) {
      int jn = j + 64;
      x = px[jn]; y = py[jn]; z = pz[jn];
    }
    #pragma unroll 8
    for (int t = 0; t < 64; t += 2) {
      float4 cA = tile[t];
      float4 cB = tile[t + 1];
      float dxa = ax - cA.x, dya = ay - cA.y, dza = az - cA.z;
      float dA = fmaf(dxa, dxa, fmaf(dya, dya, dza * dza));
      float dxb = ax - cB.x, dyb = ay - cB.y, dzb = az - cB.z;
      float dB = fmaf(dxb, dxb, fmaf(dyb, dyb, dzb * dzb));
      key_insert<K>(a, pack_key(dA, cA.w));
      key_insert<K>(b, pack_key(dB, cB.w));
    }
    j += 64;
  }
}

// Stage both per-thread lists to LDS; wave 0 finalizes half 0, wave 1
// half 1. Returns half id or -1.
template <int K>
__device__ int merge2(float (&kd0)[K], float (&kd1)[K], float* sm, int tid) {
  const int STR = K | 1;
  int q = tid & 63, wv = tid >> 6;
  #pragma unroll
  for (int m = 0; m < K; ++m) {
    sm[(wv * 128 + q) * STR + m] = kd0[m];
    sm[(wv * 128 + 64 + q) * STR + m] = kd1[m];
  }
  __syncthreads();
  if (wv == 0) {
    for (int w = 1; w < NSLICE; ++w)
      #pragma unroll
      for (int m = 0; m < K; ++m)
        key_insert<K>(kd0, sm[(w * 128 + q) * STR + m]);
    return 0;
  }
  if (wv == 1) {
    for (int w = 0; w < NSLICE; ++w) {
      if (w == 1) continue;
      #pragma unroll
      for (int m = 0; m < K; ++m)
        key_insert<K>(kd1, sm[(w * 128 + 64 + q) * STR + m]);
    }
    return 1;
  }
  return -1;
}

// 1-list-per-thread variant (k_cross): wave 0 merges all 8 slices.
template <int K>
__device__ bool merge_block(float (&kd)[K], float* sm, int tid) {
  const int STR = K | 1;
  int q = tid & 63, wv = tid >> 6;
  #pragma unroll
  for (int m = 0; m < K; ++m) sm[(wv * 64 + q) * STR + m] = kd[m];
  __syncthreads();
  if (wv) return false;
  for (int w = 1; w < NSLICE; ++w)
    #pragma unroll
    for (int m = 0; m < K; ++m)
      key_insert<K>(kd, sm[(w * 64 + q) * STR + m]);
  return true;
}

__global__ __launch_bounds__(1) void k_zero(float* out) { out[0] = 0.f; }

// pass 0 (A): self-KNN p2 k=10 -> cv2
// pass 1 (B): self-KNN p1 k=10 -> cvw + smoothness
// pass 2 (D): p2 -> warp min (dist2)
__global__ __launch_bounds__(BLOCK) void k_fused(Params P) {
  __shared__ float4 tiles[NSLICE][64];          // 8 KB
  __shared__ float sm[NSLICE * 128 * 11];       // 44 KB
  int tid = threadIdx.x, q = tid & 63, wv = tid >> 6;
  int pass = blockIdx.x / 240, r = blockIdx.x % 240;
  int s, b, i0, N, off; float alpha;
  map_block2(r, s, b, i0, N, off, alpha);
  int sl = N / NSLICE, lo = wv * sl, hi = lo + sl;
  int iA = i0 + q, iB = i0 + 64 + q;
  float4* tile = tiles[wv];

  if (pass == 0) {
    const float* p2 = P.pc2[s] + b * 3 * N;
    float ax0 = p2[iA], ay0 = p2[N + iA], az0 = p2[2 * N + iA];
    float ax1 = p2[iB], ay1 = p2[N + iB], az1 = p2[2 * N + iB];
    float a0[10], b0[10], a1[10], b1[10];
    #pragma unroll
    for (int m = 0; m < 10; ++m)
      a0[m] = b0[m] = a1[m] = b1[m] = 3.0e38f;
    scan2d<10, false, true>(p2, p2 + N, p2 + 2 * N, nullptr, nullptr,
                            nullptr, lo, hi, ax0, ay0, az0, ax1, ay1, az1,
                            a0, b0, a1, b1, tile, q);
    merge_pair<10>(a0, b0);
    merge_pair<10>(a1, b1);
    int half = merge2<10>(a0, a1, sm, tid);
    if (half < 0) return;
    const float* kd = half ? a1 : a0;
    int i = half ? iB : iA;
    float ax = half ? ax1 : ax0, ay = half ? ay1 : ay0,
          az = half ? az1 : az0;
    float sx = 0.f, sy = 0.f, sz = 0.f;
    #pragma unroll
    for (int m = 0; m < 10; ++m) {
      int j = (int)(__float_as_uint(kd[m]) & 0x1FFFu);
      sx += p2[j]; sy += p2[N + j]; sz += p2[2 * N + j];
    }
    const float inv9 = 1.f / 9.f;
    P.cv2[b * NTOT + off + i] = make_float4((sx - 10.f * ax) * inv9,
                                            (sy - 10.f * ay) * inv9,
                                            (sz - 10.f * az) * inv9, 0.f);
  } else if (pass == 1) {
    const float* p1 = P.pc1[s] + b * 3 * N;
    const float* fl = P.fl[s] + b * 3 * N;
    float ax0 = p1[iA], ay0 = p1[N + iA], az0 = p1[2 * N + iA];
    float ax1 = p1[iB], ay1 = p1[N + iB], az1 = p1[2 * N + iB];
    float a0[10], b0[10], a1[10], b1[10];
    #pragma unroll
    for (int m = 0; m < 10; ++m)
      a0[m] = b0[m] = a1[m] = b1[m] = 3.0e38f;
    scan2d<10, false, true>(p1, p1 + N, p1 + 2 * N, nullptr, nullptr,
                            nullptr, lo, hi, ax0, ay0, az0, ax1, ay1, az1,
                            a0, b0, a1, b1, tile, q);
    merge_pair<10>(a0, b0);
    merge_pair<10>(a1, b1);
    int half = merge2<10>(a0, a1, sm, tid);
    if (half < 0) return;
    const float* kd = half ? a1 : a0;
    int i = half ? iB : iA;
    float ax = half ? ax1 : ax0, ay = half ? ay1 : ay0,
          az = half ? az1 : az0;
    float fix = fl[i], fiy = fl[N + i], fiz = fl[2 * N + i];
    float wix = ax + fix, wiy = ay + fiy, wiz = az + fiz;
    float sx = 0.f, sy = 0.f, sz = 0.f, smooth = 0.f;
    float dmax = -1.f, worst = 0.f;
    #pragma unroll
    for (int m = 0; m < 10; ++m) {
      int j = (int)(__float_as_uint(kd[m]) & 0x1FFFu);
      float px = p1[j], py = p1[N + j], pz = p1[2 * N + j];
      float flx = fl[j], fly = fl[N + j], flz = fl[2 * N + j];
      sx += px + flx; sy += py + fly; sz += pz + flz;
      float ddx = px - ax, ddy = py - ay, ddz = pz - az;
      float d = fmaf(ddx, ddx, fmaf(ddy, ddy, ddz * ddz));  // exact
      float gx = flx - fix, gy = fly - fiy, gz = flz - fiz;
      float term = sqrtf(fmaf(gx, gx, fmaf(gy, gy, gz * gz)));
      smooth += term;
      if (d > dmax) { dmax = d; worst = term; }  // drop farthest (k9)
    }
    smooth -= worst;
    const float inv9 = 1.f / 9.f;
    P.cvw[b * NTOT + off + i] = make_float4((sx - 10.f * wix) * inv9,
                                            (sy - 10.f * wiy) * inv9,
                                            (sz - 10.f * wiz) * inv9, 0.f);
    float ssum = wave_sum(smooth * (1.f / 8.f));
    if (q == 0) atomicAdd(P.out, alpha * 0.5f * ssum);
  } else {
    const float* p1 = P.pc1[s] + b * 3 * N;
    const float* fl = P.fl[s] + b * 3 * N;
    const float* p2 = P.pc2[s] + b * 3 * N;
    float ax0 = p2[iA], ay0 = p2[N + iA], az0 = p2[2 * N + iA];
    float ax1 = p2[iB], ay1 = p2[N + iB], az1 = p2[2 * N + iB];
    float a0[1], b0[1], a1[1], b1[1];
    a0[0] = b0[0] = a1[0] = b1[0] = 3.0e38f;
    scan2d<1, true, false>(p1, p1 + N, p1 + 2 * N, fl, fl + N, fl + 2 * N,
                           lo, hi, ax0, ay0, az0, ax1, ay1, az1,
                           a0, b0, a1, b1, tile, q);
    sm[wv * 128 + q] = fminf(a0[0], b0[0]);
    sm[wv * 128 + 64 + q] = fminf(a1[0], b1[0]);
    __syncthreads();
    if (wv >= 2) return;
    int base = (wv == 0) ? q : 64 + q;
    float dmin = 3.0e38f;
    #pragma unroll
    for (int w = 0; w < NSLICE; ++w)
      dmin = fminf(dmin, sm[w * 128 + base]);
    float msum = wave_sum(dmin);
    if (q == 0) atomicAdd(P.out, alpha * 0.5f * msum);
  }
}

// Pass C: warp -> p2 top-5: dist1 + inverse-distance cv2 interp -> curvature
__global__ __launch_bounds__(BLOCK) void k_cross(Params P) {
  __shared__ float4 tiles[NSLICE][64];          // 8 KB
  __shared__ float sm[NSLICE * 64 * 5];         // 10 KB
  int tid = threadIdx.x, q = tid & 63, wv = tid >> 6;
  int s, b, i0, N, off; float alpha;
  map_block(blockIdx.x, s, b, i0, N, off, alpha);
  int sl = N / NSLICE, lo = wv * sl, hi = lo + sl;
  int i = i0 + q;
  const float* p1 = P.pc1[s] + b * 3 * N;
  const float* fl = P.fl[s] + b * 3 * N;
  const float* p2 = P.pc2[s] + b * 3 * N;
  float ax = p1[i] + fl[i], ay = p1[N + i] + fl[N + i],
        az = p1[2 * N + i] + fl[2 * N + i];
  float a[5], bb[5];
  #pragma unroll
  for (int m = 0; m < 5; ++m) { a[m] = 3.0e38f; bb[m] = 3.0e38f; }
  scan1d<5>(p2, p2 + N, p2 + 2 * N, lo, hi, ax, ay, az, a, bb, tiles[wv], q);
  merge_pair<5>(a, bb);
  if (!merge_block<5>(a, sm, tid)) return;
  float dist1 = 3.0e38f, wsum = 0.f, ix = 0.f, iy = 0.f, iz = 0.f;
  #pragma unroll
  for (int m = 0; m < 5; ++m) {
    int j = (int)(__float_as_uint(a[m]) & 0x1FFFu);
    float px = p2[j], py = p2[N + j], pz = p2[2 * N + j];
    float ddx = px - ax, ddy = py - ay, ddz = pz - az;
    float d = fmaf(ddx, ddx, fmaf(ddy, ddy, ddz * ddz));  // exact
    dist1 = fminf(dist1, d);
    float w = 1.f / (d + 1e-8f);
    wsum += w;
    float4 cv = P.cv2[b * NTOT + off + j];
    ix += w * cv.x; iy += w * cv.y; iz += w * cv.z;
  }
  float inv = 1.f / wsum;
  ix *= inv; iy *= inv; iz *= inv;
  float4 cw = P.cvw[b * NTOT + off + i];
  float ex = ix - cw.x, ey = iy - cw.y, ez = iz - cw.z;
  float curv = fmaf(ex, ex, fmaf(ey, ey, ez * ez));
  float csum = wave_sum(dist1 + 0.3f * curv);
  if (q == 0) atomicAdd(P.out, alpha * 0.5f * csum);
}

extern "C" void kernel_launch(void* const* d_in, const int* in_sizes, int n_in,
                              void* d_out, int out_size, void* d_ws,
                              size_t ws_size, hipStream_t stream) {
  Params P;
  for (int s = 0; s < 4; ++s) {
    P.pc1[s] = (const float*)d_in[s];
    P.pc2[s] = (const float*)d_in[4 + s];
    P.fl[s]  = (const float*)d_in[8 + s];
  }
  P.cv2 = (float4*)d_ws;
  P.cvw = (float4*)((char*)d_ws + (size_t)2 * NTOT * sizeof(float4));
  P.out = (float*)d_out;

  k_zero<<<dim3(1), dim3(1), 0, stream>>>(P.out);
  k_fused<<<dim3(720), dim3(BLOCK), 0, stream>>>(P);
  k_cross<<<dim3(480), dim3(BLOCK), 0, stream>>>(P);
}

// Round 8
// 326.887 us; speedup vs baseline: 2.2635x; 1.0975x over previous
//
#include <hip/hip_runtime.h>
#include <math.h>

// PointPWC multi-scale loss. B=2, scales N={8192,4096,2048,1024}.
// Inputs (B,3,N) fp32 channel-major: pc1_0..3, pc2_0..3, flow_0..3.
// Output: single fp32 scalar.
//
// R8: uniform work quanta. R7 counters showed all blocks co-resident with
// 8x work imbalance between scales -> makespan set by heavy s0 blocks at
// ~2 waves/SIMD (occupancy 28%). Now every wave = exactly 64 queries x
// 1024 candidates; block = 8 waves of one scale (s0: 1 qgroup x 8 ranges,
// s1: 2x4, s2: 4x2, s3: 8x1; merge intra-block, leader = range-0 wave).
// 340 identical blocks/pass; LDS 30.7KB + launch_bounds(512,8) -> 4
// blocks/CU = 100% occupancy, near-zero tail.

#define BLOCK 512
#define UNIT 1024    // candidates per wave-unit
#define NTOT 15360   // 8192+4096+2048+1024
#define MASKC 0xFFFFE000u
#define PB 340       // blocks per pass

typedef unsigned int uint;

struct Params {
  const float* pc1[4];
  const float* pc2[4];
  const float* fl[4];
  float4* cv2;   // [B][NTOT]
  float4* cvw;   // [B][NTOT]
  float* out;
};

// r in [0,340) -> scale s, batch b, query-group base i0, candidate lo.
__device__ __forceinline__ void decode(int r, int wv, int& s, int& b,
                                       int& i0, int& lo, int& N, int& cpw,
                                       int& off, float& alpha) {
  int rr;
  if (r < 256)      { s = 0; rr = r; }
  else if (r < 320) { s = 1; rr = r - 256; }
  else if (r < 336) { s = 2; rr = r - 320; }
  else              { s = 3; rr = r - 336; }
  N = 8192 >> s;
  cpw = 8 >> s;                       // candidate-ranges per qgroup
  int perb = 128 >> (2 * s);          // blocks per batch
  b = rr >> (7 - 2 * s);
  int chunk = rr & (perb - 1);
  int qg = (chunk << s) + (wv >> (3 - s));
  i0 = qg << 6;
  lo = (wv & (cpw - 1)) << 10;
  off = 16384 - (16384 >> s);         // {0, 8192, 12288, 14336}
  alpha = 0.02f * (float)(1 << s);
}

__device__ __forceinline__ float wave_sum(float v) {
  #pragma unroll
  for (int o = 32; o; o >>= 1) v += __shfl_down(v, o, 64);
  return v;
}

// Branchless insert of key kf into sorted-ascending kd[K].
template <int K>
__device__ __forceinline__ void key_insert(float (&kd)[K], float kf) {
  #pragma unroll
  for (int m = K - 1; m >= 1; --m)
    kd[m] = __builtin_amdgcn_fmed3f(kf, kd[m - 1], kd[m]);
  kd[0] = fminf(kd[0], kf);
}

template <int K>
__device__ __forceinline__ void merge_pair(float (&a)[K], const float (&b)[K]) {
  #pragma unroll
  for (int m = 0; m < K; ++m) key_insert<K>(a, b[m]);
}

__device__ __forceinline__ float pack_key(float d, float iw) {
  return __uint_as_float((__float_as_uint(d) & MASKC) | __float_as_uint(iw));
}

// One unit: 1 query/thread, 2 alternating chains (even/odd candidates),
// candidates broadcast from this wave's private LDS tile.
template <int K, bool WARP, bool PACK>
__device__ void scan_u(const float* px, const float* py, const float* pz,
                       const float* fx, const float* fy, const float* fz,
                       int lo, float ax, float ay, float az,
                       float (&a)[K], float (&b)[K], float4* tile,
                       int lane) {
  int j = lo + lane;
  float x = px[j], y = py[j], z = pz[j];
  if (WARP) { x += fx[j]; y += fy[j]; z += fz[j]; }
  for (int c0 = lo; c0 < lo + UNIT; c0 += 64) {
    tile[lane] = make_float4(x, y, z, __uint_as_float((uint)(c0 + lane)));
    // same-wave fill->broadcast: DS pipe is in-order per wave
    asm volatile("s_waitcnt lgkmcnt(0)" ::: "memory");
    if (c0 + 64 < lo + UNIT) {   // prefetch next tile (rides vmcnt leash)
      int jn = j + 64;
      x = px[jn]; y = py[jn]; z = pz[jn];
      if (WARP) { x += fx[jn]; y += fy[jn]; z += fz[jn]; }
    }
    #pragma unroll 8
    for (int t = 0; t < 64; t += 2) {
      float4 cA = tile[t];
      float4 cB = tile[t + 1];
      float dxa = ax - cA.x, dya = ay - cA.y, dza = az - cA.z;
      float dA = fmaf(dxa, dxa, fmaf(dya, dya, dza * dza));
      float dxb = ax - cB.x, dyb = ay - cB.y, dzb = az - cB.z;
      float dB = fmaf(dxb, dxb, fmaf(dyb, dyb, dzb * dzb));
      if (PACK) {
        key_insert<K>(a, pack_key(dA, cA.w));
        key_insert<K>(b, pack_key(dB, cB.w));
      } else {
        a[0] = fminf(a[0], dA);
        b[0] = fminf(b[0], dB);
      }
    }
    j += 64;
  }
}

// Stage per-thread list; group leader (wave with cr==0) merges its
// qgroup's cpw lists. Returns true for leader threads.
template <int K>
__device__ __forceinline__ bool merge_group(float (&a)[K], float* sm,
                                            int tid, int cpw) {
  const int STR = K | 1;   // odd stride: 2-way bank aliasing only (free)
  int q = tid & 63, wv = tid >> 6;
  #pragma unroll
  for (int m = 0; m < K; ++m) sm[(wv * 64 + q) * STR + m] = a[m];
  __syncthreads();
  if (wv & (cpw - 1)) return false;
  for (int w = wv + 1; w < wv + cpw; ++w)
    #pragma unroll
    for (int m = 0; m < K; ++m)
      key_insert<K>(a, sm[(w * 64 + q) * STR + m]);
  return true;
}

__global__ __launch_bounds__(1) void k_zero(float* out) { out[0] = 0.f; }

// pass 0 (A): self-KNN p2 k=10 -> cv2
// pass 1 (B): self-KNN p1 k=10 -> cvw + smoothness
// pass 2 (D): p2 -> warp min (dist2)
__global__ __launch_bounds__(BLOCK, 8) void k_fused(Params P) {
  __shared__ float4 tiles[8][64];        // 8 KB
  __shared__ float sm[8 * 64 * 11];      // 22.5 KB
  int tid = threadIdx.x, q = tid & 63, wv = tid >> 6;
  int pass = blockIdx.x / PB, r = blockIdx.x % PB;
  int s, b, i0, lo, N, cpw, off; float alpha;
  decode(r, wv, s, b, i0, lo, N, cpw, off, alpha);
  int i = i0 + q;
  float4* tile = tiles[wv];

  if (pass == 0) {
    const float* p2 = P.pc2[s] + b * 3 * N;
    float ax = p2[i], ay = p2[N + i], az = p2[2 * N + i];
    float a[10], bb[10];
    #pragma unroll
    for (int m = 0; m < 10; ++m) { a[m] = 3.0e38f; bb[m] = 3.0e38f; }
    scan_u<10, false, true>(p2, p2 + N, p2 + 2 * N, nullptr, nullptr,
                            nullptr, lo, ax, ay, az, a, bb, tile, q);
    merge_pair<10>(a, bb);
    if (!merge_group<10>(a, sm, tid, cpw)) return;
    float sx = 0.f, sy = 0.f, sz = 0.f;
    #pragma unroll
    for (int m = 0; m < 10; ++m) {
      int j = (int)(__float_as_uint(a[m]) & 0x1FFFu);
      sx += p2[j]; sy += p2[N + j]; sz += p2[2 * N + j];
    }
    const float inv9 = 1.f / 9.f;
    P.cv2[b * NTOT + off + i] = make_float4((sx - 10.f * ax) * inv9,
                                            (sy - 10.f * ay) * inv9,
                                            (sz - 10.f * az) * inv9, 0.f);
  } else if (pass == 1) {
    const float* p1 = P.pc1[s] + b * 3 * N;
    const float* fl = P.fl[s] + b * 3 * N;
    float ax = p1[i], ay = p1[N + i], az = p1[2 * N + i];
    float a[10], bb[10];
    #pragma unroll
    for (int m = 0; m < 10; ++m) { a[m] = 3.0e38f; bb[m] = 3.0e38f; }
    scan_u<10, false, true>(p1, p1 + N, p1 + 2 * N, nullptr, nullptr,
                            nullptr, lo, ax, ay, az, a, bb, tile, q);
    merge_pair<10>(a, bb);
    if (!merge_group<10>(a, sm, tid, cpw)) return;
    float fix = fl[i], fiy = fl[N + i], fiz = fl[2 * N + i];
    float wix = ax + fix, wiy = ay + fiy, wiz = az + fiz;
    float sx = 0.f, sy = 0.f, sz = 0.f, smooth = 0.f;
    float dmax = -1.f, worst = 0.f;
    #pragma unroll
    for (int m = 0; m < 10; ++m) {
      int j = (int)(__float_as_uint(a[m]) & 0x1FFFu);
      float px = p1[j], py = p1[N + j], pz = p1[2 * N + j];
      float flx = fl[j], fly = fl[N + j], flz = fl[2 * N + j];
      sx += px + flx; sy += py + fly; sz += pz + flz;
      float ddx = px - ax, ddy = py - ay, ddz = pz - az;
      float d = fmaf(ddx, ddx, fmaf(ddy, ddy, ddz * ddz));  // exact
      float gx = flx - fix, gy = fly - fiy, gz = flz - fiz;
      float term = sqrtf(fmaf(gx, gx, fmaf(gy, gy, gz * gz)));
      smooth += term;
      if (d > dmax) { dmax = d; worst = term; }  // drop farthest (k9)
    }
    smooth -= worst;
    const float inv9 = 1.f / 9.f;
    P.cvw[b * NTOT + off + i] = make_float4((sx - 10.f * wix) * inv9,
                                            (sy - 10.f * wiy) * inv9,
                                            (sz - 10.f * wiz) * inv9, 0.f);
    float ssum = wave_sum(smooth * (1.f / 8.f));
    if (q == 0) atomicAdd(P.out, alpha * 0.5f * ssum);
  } else {
    const float* p1 = P.pc1[s] + b * 3 * N;
    const float* fl = P.fl[s] + b * 3 * N;
    const float* p2 = P.pc2[s] + b * 3 * N;
    float ax = p2[i], ay = p2[N + i], az = p2[2 * N + i];
    float a[1], bb[1];
    a[0] = 3.0e38f; bb[0] = 3.0e38f;
    scan_u<1, true, false>(p1, p1 + N, p1 + 2 * N, fl, fl + N, fl + 2 * N,
                           lo, ax, ay, az, a, bb, tile, q);
    merge_pair<1>(a, bb);
    if (!merge_group<1>(a, sm, tid, cpw)) return;
    float msum = wave_sum(a[0]);
    if (q == 0) atomicAdd(P.out, alpha * 0.5f * msum);
  }
}

// Pass C: warp -> p2 top-5: dist1 + inverse-distance cv2 interp -> curvature
__global__ __launch_bounds__(BLOCK, 8) void k_cross(Params P) {
  __shared__ float4 tiles[8][64];
  __shared__ float sm[8 * 64 * 5];
  int tid = threadIdx.x, q = tid & 63, wv = tid >> 6;
  int s, b, i0, lo, N, cpw, off; float alpha;
  decode(blockIdx.x, wv, s, b, i0, lo, N, cpw, off, alpha);
  int i = i0 + q;
  const float* p1 = P.pc1[s] + b * 3 * N;
  const float* fl = P.fl[s] + b * 3 * N;
  const float* p2 = P.pc2[s] + b * 3 * N;
  float ax = p1[i] + fl[i], ay = p1[N + i] + fl[N + i],
        az = p1[2 * N + i] + fl[2 * N + i];
  float a[5], bb[5];
  #pragma unroll
  for (int m = 0; m < 5; ++m) { a[m] = 3.0e38f; bb[m] = 3.0e38f; }
  scan_u<5, false, true>(p2, p2 + N, p2 + 2 * N, nullptr, nullptr, nullptr,
                         lo, ax, ay, az, a, bb, tiles[wv], q);
  merge_pair<5>(a, bb);
  if (!merge_group<5>(a, sm, tid, cpw)) return;
  float dist1 = 3.0e38f, wsum = 0.f, ix = 0.f, iy = 0.f, iz = 0.f;
  #pragma unroll
  for (int m = 0; m < 5; ++m) {
    int j = (int)(__float_as_uint(a[m]) & 0x1FFFu);
    float px = p2[j], py = p2[N + j], pz = p2[2 * N + j];
    float ddx = px - ax, ddy = py - ay, ddz = pz - az;
    float d = fmaf(ddx, ddx, fmaf(ddy, ddy, ddz * ddz));  // exact
    dist1 = fminf(dist1, d);
    float w = 1.f / (d + 1e-8f);
    wsum += w;
    float4 cv = P.cv2[b * NTOT + off + j];
    ix += w * cv.x; iy += w * cv.y; iz += w * cv.z;
  }
  float inv = 1.f / wsum;
  ix *= inv; iy *= inv; iz *= inv;
  float4 cw = P.cvw[b * NTOT + off + i];
  float ex = ix - cw.x, ey = iy - cw.y, ez = iz - cw.z;
  float curv = fmaf(ex, ex, fmaf(ey, ey, ez * ez));
  float csum = wave_sum(dist1 + 0.3f * curv);
  if (q == 0) atomicAdd(P.out, alpha * 0.5f * csum);
}

extern "C" void kernel_launch(void* const* d_in, const int* in_sizes, int n_in,
                              void* d_out, int out_size, void* d_ws,
                              size_t ws_size, hipStream_t stream) {
  Params P;
  for (int s = 0; s < 4; ++s) {
    P.pc1[s] = (const float*)d_in[s];
    P.pc2[s] = (const float*)d_in[4 + s];
    P.fl[s]  = (const float*)d_in[8 + s];
  }
  P.cv2 = (float4*)d_ws;
  P.cvw = (float4*)((char*)d_ws + (size_t)2 * NTOT * sizeof(float4));
  P.out = (float*)d_out;

  k_zero<<<dim3(1), dim3(1), 0, stream>>>(P.out);
  k_fused<<<dim3(3 * PB), dim3(BLOCK), 0, stream>>>(P);
  k_cross<<<dim3(PB), dim3(BLOCK), 0, stream>>>(P);
}